// Round 4
// baseline (91.771 us; speedup 1.0000x reference)
//
#include <hip/hip_runtime.h>
#include <hip/hip_fp16.h>

// QAvgPool2d: 2x2/stride-2 avg pool with fp16 (e5m10) RNE quantization at
// every accumulation step. Input fp32 (32,256,112,112), output fp32
// (32,256,56,56). Streaming: 411 MB read + 103 MB write, no reuse.
// R3: 8 outputs/thread + pairwise lane-exchange so stores are float4.

constexpr int B  = 32, C = 256, H = 112, W = 112;
constexpr int OH = 56, OW = 56;
constexpr int HW   = H * W;        // 12544
constexpr int OHOW = OH * OW;      // 3136
constexpr int NOUT = B * C * OH * OW;
constexpr int PW   = OW / 2;       // 28 float4-columns per input row
constexpr int R8   = OH / 4;       // 14 groups of 4 output rows (8 input rows)

typedef float vfloat4 __attribute__((ext_vector_type(4)));
typedef float vfloat2 __attribute__((ext_vector_type(2)));

// fp16 quantize: float -> half (RNE, HW v_cvt) -> float. Matches
// float_quantize(EXP=5, MAN=10) incl. subnormals; saturation unreachable here.
__device__ __forceinline__ float q16(float v) {
    return __half2float(__float2half(v));
}

__device__ __forceinline__ float pool4(float x00, float x01, float x10, float x11) {
    float acc = q16(x00);          // reference order (0,0),(0,1),(1,0),(1,1)
    acc = q16(acc + x01);
    acc = q16(acc + x10);
    acc = q16(acc + x11);
    return q16(acc * 0.25f);
}

__global__ __launch_bounds__(256)
void qavgpool2d_kernel(const float* __restrict__ x, float* __restrict__ y) {
    int t = blockIdx.x * blockDim.x + threadIdx.x;   // 8 outputs per thread

    int pw  = t % PW;              // float4 column within input rows
    int tmp = t / PW;
    int r8  = tmp % R8;            // 4-output-row group
    int bc  = tmp / R8;            // fused (b,c)

    const float* xb = x + (size_t)bc * HW + (r8 * 8) * W + pw * 4;

    // 8 input rows, one aligned float4 each; lanes byte-contiguous per instr.
    vfloat4 a[8];
    #pragma unroll
    for (int k = 0; k < 8; ++k)
        a[k] = __builtin_nontemporal_load(reinterpret_cast<const vfloat4*>(xb + (size_t)k * W));

    // o[r]: two pooled outputs for output row r8*4+r, cols pw*2, pw*2+1
    vfloat2 o[4];
    #pragma unroll
    for (int r = 0; r < 4; ++r) {
        o[r].x = pool4(a[2*r].x, a[2*r].y, a[2*r+1].x, a[2*r+1].y);
        o[r].y = pool4(a[2*r].z, a[2*r].w, a[2*r+1].z, a[2*r+1].w);
    }

    // Pairwise exchange: even lane gathers both row-even float2s (-> float4),
    // odd lane gathers both row-odd float2s. Pairs (2i,2i+1) share bc/r8 and
    // have pw = {p, p+1}, p even (PW=28 even, pairs start at even t).
    const bool odd = (threadIdx.x & 1);
    vfloat2 s0 = odd ? o[0] : o[1];
    vfloat2 r0; r0.x = __shfl_xor(s0.x, 1, 64); r0.y = __shfl_xor(s0.y, 1, 64);
    vfloat2 s1 = odd ? o[2] : o[3];
    vfloat2 r1; r1.x = __shfl_xor(s1.x, 1, 64); r1.y = __shfl_xor(s1.y, 1, 64);

    vfloat4 st0, st1;
    if (odd) { st0 = vfloat4{r0.x, r0.y, o[1].x, o[1].y};
               st1 = vfloat4{r1.x, r1.y, o[3].x, o[3].y}; }
    else     { st0 = vfloat4{o[0].x, o[0].y, r0.x, r0.y};
               st1 = vfloat4{o[2].x, o[2].y, r1.x, r1.y}; }

    // even lane -> rows +0,+2 ; odd lane -> rows +1,+3 of the 4-row group
    int row = r8 * 4 + (odd ? 1 : 0);
    float* yb = y + (size_t)bc * OHOW + row * OW + (pw & ~1) * 2;
    __builtin_nontemporal_store(st0, reinterpret_cast<vfloat4*>(yb));
    __builtin_nontemporal_store(st1, reinterpret_cast<vfloat4*>(yb + 2 * OW));
}

extern "C" void kernel_launch(void* const* d_in, const int* in_sizes, int n_in,
                              void* d_out, int out_size, void* d_ws, size_t ws_size,
                              hipStream_t stream) {
    const float* x = (const float*)d_in[0];
    float*       y = (float*)d_out;

    constexpr int threads = 256;
    constexpr int nthreads_total = NOUT / 8;          // 3,211,264
    constexpr int blocks = nthreads_total / threads;  // 12,544 exactly

    qavgpool2d_kernel<<<blocks, threads, 0, stream>>>(x, y);
}

// Round 5
// 87.710 us; speedup vs baseline: 1.0463x; 1.0463x over previous
//
#include <hip/hip_runtime.h>
#include <hip/hip_fp16.h>

// QAvgPool2d: 2x2/stride-2 avg pool with fp16 (e5m10) RNE quantization at
// every accumulation step. Input fp32 (32,256,112,112), output fp32
// (32,256,56,56). Pure streaming: 411 MB read + 103 MB write, no reuse.
// R4 = revert to R2 (87.7 us): R3's shfl-repacked float4 stores regressed
// (91.8 us) — shuffles serialized the store tail; store width wasn't the
// bottleneck at 20% of traffic.

constexpr int B  = 32, C = 256, H = 112, W = 112;
constexpr int OH = 56, OW = 56;
constexpr int HW   = H * W;        // 12544
constexpr int OHOW = OH * OW;      // 3136
constexpr int NOUT = B * C * OH * OW;
constexpr int PW   = OW / 2;       // 28 float4-columns per input row (2 outputs each)
constexpr int RP   = OH / 2;       // 28 output-row pairs

// Native clang vectors — accepted by __builtin_nontemporal_{load,store}.
typedef float vfloat4 __attribute__((ext_vector_type(4)));
typedef float vfloat2 __attribute__((ext_vector_type(2)));

// fp16 quantize: float -> half (RNE, HW v_cvt) -> float. Matches
// float_quantize(EXP=5, MAN=10) incl. subnormals; saturation unreachable here.
__device__ __forceinline__ float q16(float v) {
    return __half2float(__float2half(v));
}

__device__ __forceinline__ float pool4(float x00, float x01, float x10, float x11) {
    float acc = q16(x00);          // reference order (0,0),(0,1),(1,0),(1,1)
    acc = q16(acc + x01);
    acc = q16(acc + x10);
    acc = q16(acc + x11);
    return q16(acc * 0.25f);
}

__global__ __launch_bounds__(256)
void qavgpool2d_kernel(const float* __restrict__ x, float* __restrict__ y) {
    int t = blockIdx.x * blockDim.x + threadIdx.x;  // 4 outputs per thread

    // Lane-stride-16B mapping: one float4 per input row, two row-pairs deep.
    int pw  = t % PW;              // which float4 within the row
    int tmp = t / PW;
    int r2  = tmp % RP;            // output row-pair index
    int bc  = tmp / RP;            // fused (b,c)

    const float* xb = x + (size_t)bc * HW + (r2 * 4) * W + pw * 4;

    // Four input rows, each one aligned float4; consecutive lanes are
    // byte-contiguous within each instruction (448 B runs, no gaps).
    vfloat4 a0 = __builtin_nontemporal_load(reinterpret_cast<const vfloat4*>(xb));
    vfloat4 a1 = __builtin_nontemporal_load(reinterpret_cast<const vfloat4*>(xb + W));
    vfloat4 a2 = __builtin_nontemporal_load(reinterpret_cast<const vfloat4*>(xb + 2 * W));
    vfloat4 a3 = __builtin_nontemporal_load(reinterpret_cast<const vfloat4*>(xb + 3 * W));

    vfloat2 o0, o1;
    o0.x = pool4(a0.x, a0.y, a1.x, a1.y);
    o0.y = pool4(a0.z, a0.w, a1.z, a1.w);
    o1.x = pool4(a2.x, a2.y, a3.x, a3.y);
    o1.y = pool4(a2.z, a2.w, a3.z, a3.w);

    float* yb = y + (size_t)bc * OHOW + (r2 * 2) * OW + pw * 2;
    __builtin_nontemporal_store(o0, reinterpret_cast<vfloat2*>(yb));
    __builtin_nontemporal_store(o1, reinterpret_cast<vfloat2*>(yb + OW));
}

extern "C" void kernel_launch(void* const* d_in, const int* in_sizes, int n_in,
                              void* d_out, int out_size, void* d_ws, size_t ws_size,
                              hipStream_t stream) {
    const float* x = (const float*)d_in[0];
    float*       y = (float*)d_out;

    constexpr int threads = 256;
    constexpr int nthreads_total = NOUT / 4;          // 6,422,528
    constexpr int blocks = nthreads_total / threads;  // 25,088 exactly

    qavgpool2d_kernel<<<blocks, threads, 0, stream>>>(x, y);
}